// Round 5
// baseline (719.079 us; speedup 1.0000x reference)
//
#include <hip/hip_runtime.h>

#define LAT 128
#define CAP 64    // per-node LDS cache of exp(att); deg>CAP falls back to recompute

// ---------------- projection GEMM v4: k-tiled staging, 26 KB LDS ----------------
// Grid (N/64, 3 mats). Per block: 64 nodes x 128 cols; K staged in 4 tiles of 32.
// Thread tile: 4 nodes (nl+16i) x 8 cols (j0*4..+3 and 64+j0*4..+3).
__global__ __launch_bounds__(256) void proj_kernel(
    const float* __restrict__ A,
    const float* __restrict__ Wq, const float* __restrict__ Wk, const float* __restrict__ Wv,
    float* __restrict__ Cq, float* __restrict__ Ckv,
    int N)
{
  __shared__ float eL[64][36];    // 64 nodes x 32 k (+4 pad)  = 9.2 KB
  __shared__ float wL[32][132];   // 32 k x 128 cols (+4 pad)  = 16.9 KB
  const int t = threadIdx.x;
  const int n0 = blockIdx.x * 64;
  const int mat = blockIdx.y;           // 0=q 1=k 2=v
  const float* W = (mat == 0) ? Wq : (mat == 1) ? Wk : Wv;

  const int nl = t & 15;          // nodes nl, nl+16, nl+32, nl+48
  const int j0 = t >> 4;          // col groups j0*4 and 64+j0*4
  float acc[4][8] = {};

  for (int kt = 0; kt < 4; ++kt) {
    __syncthreads();
    // stage eL: 64 nodes x 32 k = 512 float4, 2/thread (coalesced)
    #pragma unroll
    for (int it = 0; it < 2; ++it) {
      int flat = (it * 256 + t) * 4;
      int n = flat >> 5, kk = flat & 31;
      float4 v = make_float4(0.f, 0.f, 0.f, 0.f);
      if (n0 + n < N) v = *(const float4*)(A + (size_t)(n0 + n) * LAT + kt * 32 + kk);
      *(float4*)&eL[n][kk] = v;
    }
    // stage wL: 32 k x 128 cols = 1024 float4, 4/thread (coalesced)
    #pragma unroll
    for (int it = 0; it < 4; ++it) {
      int flat = (it * 256 + t) * 4;
      int kk = flat >> 7, c = flat & 127;
      *(float4*)&wL[kk][c] = *(const float4*)(W + (size_t)(kt * 32 + kk) * LAT + c);
    }
    __syncthreads();
    #pragma unroll 4
    for (int kk = 0; kk < 32; kk += 2) {
      float4 wa0 = *(float4*)&wL[kk][j0 * 4];
      float4 wb0 = *(float4*)&wL[kk][64 + j0 * 4];
      float4 wa1 = *(float4*)&wL[kk + 1][j0 * 4];
      float4 wb1 = *(float4*)&wL[kk + 1][64 + j0 * 4];
      #pragma unroll
      for (int i = 0; i < 4; ++i) {
        float2 e = *(float2*)&eL[nl + 16 * i][kk];
        acc[i][0] += e.x * wa0.x + e.y * wa1.x;
        acc[i][1] += e.x * wa0.y + e.y * wa1.y;
        acc[i][2] += e.x * wa0.z + e.y * wa1.z;
        acc[i][3] += e.x * wa0.w + e.y * wa1.w;
        acc[i][4] += e.x * wb0.x + e.y * wb1.x;
        acc[i][5] += e.x * wb0.y + e.y * wb1.y;
        acc[i][6] += e.x * wb0.z + e.y * wb1.z;
        acc[i][7] += e.x * wb0.w + e.y * wb1.w;
      }
    }
  }

  #pragma unroll
  for (int i = 0; i < 4; ++i) {
    int n = n0 + nl + 16 * i;
    if (n < N) {
      float* C = (mat == 0) ? (Cq + (size_t)n * LAT)
                            : (Ckv + (size_t)n * 256 + (mat == 2 ? 128 : 0));
      *(float4*)(C + j0 * 4)      = make_float4(acc[i][0], acc[i][1], acc[i][2], acc[i][3]);
      *(float4*)(C + 64 + j0 * 4) = make_float4(acc[i][4], acc[i][5], acc[i][6], acc[i][7]);
    }
  }
}

// ---------------- CSR build ----------------
__global__ __launch_bounds__(256) void deg_kernel(const int* __restrict__ rows,
                                                  int* __restrict__ counts, int E) {
  int i = blockIdx.x * 256 + threadIdx.x;
  if (i < E) atomicAdd(&counts[rows[i]], 1);
}

__global__ __launch_bounds__(1024) void scan1_kernel(const int* __restrict__ counts,
                                                     int* __restrict__ starts,
                                                     int* __restrict__ bsums, int N) {
  __shared__ int sh[1024];
  int t = threadIdx.x;
  int i = blockIdx.x * 1024 + t;
  int v = (i < N) ? counts[i] : 0;
  sh[t] = v; __syncthreads();
  for (int off = 1; off < 1024; off <<= 1) {
    int x = (t >= off) ? sh[t - off] : 0;
    __syncthreads();
    sh[t] += x;
    __syncthreads();
  }
  if (i < N) starts[i] = sh[t] - v;
  if (t == 1023) bsums[blockIdx.x] = sh[t];
}

__global__ __launch_bounds__(1024) void scan2_kernel(int* __restrict__ bsums, int nb) {
  __shared__ int sh[1024];
  int t = threadIdx.x;
  int v = (t < nb) ? bsums[t] : 0;
  sh[t] = v; __syncthreads();
  for (int off = 1; off < 1024; off <<= 1) {
    int x = (t >= off) ? sh[t - off] : 0;
    __syncthreads();
    sh[t] += x;
    __syncthreads();
  }
  if (t < nb) bsums[t] = sh[t] - v;
}

__global__ __launch_bounds__(256) void scan3_kernel(int* __restrict__ starts,
                                                    const int* __restrict__ bsums,
                                                    int* __restrict__ cursor, int N) {
  int i = blockIdx.x * 256 + threadIdx.x;
  if (i < N) {
    int s = starts[i] + bsums[i >> 10];
    starts[i] = s;
    cursor[i] = s;
  }
}

__global__ __launch_bounds__(256) void fill_kernel(const int* __restrict__ rows,
                                                   const int* __restrict__ cols,
                                                   int* __restrict__ cursor,
                                                   int2* __restrict__ epack, int E) {
  int i = blockIdx.x * 256 + threadIdx.x;
  if (i < E) {
    int p = atomicAdd(&cursor[rows[i]], 1);
    epack[p] = make_int2(i, cols[i]);   // one 8B scattered write (was two 4B)
  }
}

// ---------------- fused attention v2: wave/node, 8 edges/step, 8 lanes/edge ----
// lane = (s,g): s=lane>>3 edge slot, g=lane&7 owns dims g*16..g*16+15 (head g>>1).
// Per step: 8 edges, 8 KB of gathers in flight; head dot = 16 MAC + 1 shfl_xor.
__global__ __launch_bounds__(256) void attn_kernel(
    const float* __restrict__ KV,
    const int* __restrict__ starts, const int* __restrict__ counts,
    const int2* __restrict__ epack,
    float* __restrict__ outRes,    // in: Q rows (stashed); out: result
    float* __restrict__ outAtt,    // normalized attention [E][4]
    int N)
{
  __shared__ float eaL[4][CAP][4];   // [wave][edge idx][head]
  const int w = threadIdx.x >> 6;
  const int lane = threadIdx.x & 63;
  const int n = blockIdx.x * 4 + w;
  if (n >= N) return;                 // whole-wave exit; no __syncthreads in kernel
  const int g = lane & 7;
  const int s = lane >> 3;
  const int start = starts[n];
  const int deg = counts[n];

  const float* qp = outRes + (size_t)n * LAT + g * 16;
  const float4 q0 = *(const float4*)(qp + 0);
  const float4 q1 = *(const float4*)(qp + 4);
  const float4 q2 = *(const float4*)(qp + 8);
  const float4 q3 = *(const float4*)(qp + 12);

  float denom = 0.f;
  float acc[16] = {};

  const int steps = (deg + 7) >> 3;
  int2 ep = make_int2(0, 0);
  if (deg > 0) ep = epack[start + (s < deg ? s : deg - 1)];

  for (int st = 0; st < steps; ++st) {
    const int j = st * 8 + s;
    const bool valid = (j < deg);
    const int c = ep.y;
    const int e = ep.x;
    // prefetch next step's index (clamped; valid flag gates use)
    int jn = j + 8;
    ep = epack[start + (jn < deg ? jn : deg - 1)];

    const float* kv = KV + (size_t)c * 256 + g * 16;
    float4 k0 = *(const float4*)(kv + 0);
    float4 k1 = *(const float4*)(kv + 4);
    float4 k2 = *(const float4*)(kv + 8);
    float4 k3 = *(const float4*)(kv + 12);
    float4 v0 = *(const float4*)(kv + 128);
    float4 v1 = *(const float4*)(kv + 132);
    float4 v2 = *(const float4*)(kv + 136);
    float4 v3 = *(const float4*)(kv + 140);

    float p = q0.x * k0.x + q0.y * k0.y + q0.z * k0.z + q0.w * k0.w
            + q1.x * k1.x + q1.y * k1.y + q1.z * k1.z + q1.w * k1.w
            + q2.x * k2.x + q2.y * k2.y + q2.z * k2.z + q2.w * k2.w
            + q3.x * k3.x + q3.y * k3.y + q3.z * k3.z + q3.w * k3.w;
    p += __shfl_xor(p, 1);               // pair (g=2h, 2h+1): head dot complete
    p = fminf(fmaxf(p, -10.f), 10.f);
    float ea = valid ? __expf(p) : 0.f;
    denom += ea;
    acc[0]  += ea * v0.x; acc[1]  += ea * v0.y; acc[2]  += ea * v0.z; acc[3]  += ea * v0.w;
    acc[4]  += ea * v1.x; acc[5]  += ea * v1.y; acc[6]  += ea * v1.z; acc[7]  += ea * v1.w;
    acc[8]  += ea * v2.x; acc[9]  += ea * v2.y; acc[10] += ea * v2.z; acc[11] += ea * v2.w;
    acc[12] += ea * v3.x; acc[13] += ea * v3.y; acc[14] += ea * v3.z; acc[15] += ea * v3.w;
    if (valid && !(g & 1) && j < CAP) eaL[w][j][g >> 1] = ea;
  }

  // cross-slot reduction (s = bits 3,4,5)
  denom += __shfl_xor(denom, 8);
  denom += __shfl_xor(denom, 16);
  denom += __shfl_xor(denom, 32);
  #pragma unroll
  for (int i = 0; i < 16; ++i) {
    acc[i] += __shfl_xor(acc[i], 8);
    acc[i] += __shfl_xor(acc[i], 16);
    acc[i] += __shfl_xor(acc[i], 32);
  }
  const float rden = 1.f / (denom + 1e-8f);

  // per-head reciprocal denominators (from s=0 lanes g=0,2,4,6)
  const float r0 = __shfl(rden, 0);
  const float r1 = __shfl(rden, 2);
  const float r2 = __shfl(rden, 4);
  const float r3 = __shfl(rden, 6);

  // epilogue: normalized att for cached edges (one float4 scatter per edge)
  const int capped = deg < CAP ? deg : CAP;
  for (int j = lane; j < capped; j += 64) {
    int e = epack[start + j].x;
    float4 a = *(float4*)&eaL[w][j][0];
    a.x *= r0; a.y *= r1; a.z *= r2; a.w *= r3;
    *(float4*)(outAtt + (size_t)e * 4) = a;
  }

  // fallback for deg > CAP (essentially never for Poisson(16) degrees).
  // Runs BEFORE outRes is overwritten, reading the full Q row from global.
  for (int j = CAP + lane; j < deg; j += 64) {
    int2 epf = epack[start + j];
    const float* kvp = KV + (size_t)epf.y * 256;
    const float* qr = outRes + (size_t)n * LAT;
    float4 o;
    float* op = (float*)&o;
    #pragma unroll
    for (int h = 0; h < 4; ++h) {
      float d = 0.f;
      for (int dd = 0; dd < 32; ++dd) d += qr[h * 32 + dd] * kvp[h * 32 + dd];
      d = fminf(fmaxf(d, -10.f), 10.f);
      op[h] = __expf(d) * (h == 0 ? r0 : h == 1 ? r1 : h == 2 ? r2 : r3);
    }
    *(float4*)(outAtt + (size_t)epf.x * 4) = o;
  }

  // result write: s=0 lanes own dims g*16..g*16+15
  if (lane < 8) {
    float* rp = outRes + (size_t)n * LAT + g * 16;
    *(float4*)(rp + 0)  = make_float4(acc[0] * rden,  acc[1] * rden,  acc[2] * rden,  acc[3] * rden);
    *(float4*)(rp + 4)  = make_float4(acc[4] * rden,  acc[5] * rden,  acc[6] * rden,  acc[7] * rden);
    *(float4*)(rp + 8)  = make_float4(acc[8] * rden,  acc[9] * rden,  acc[10] * rden, acc[11] * rden);
    *(float4*)(rp + 12) = make_float4(acc[12] * rden, acc[13] * rden, acc[14] * rden, acc[15] * rden);
  }
}

// ---------------- launch ----------------
extern "C" void kernel_launch(void* const* d_in, const int* in_sizes, int n_in,
                              void* d_out, int out_size, void* d_ws, size_t ws_size,
                              hipStream_t stream) {
  const float* embeds = (const float*)d_in[0];
  const float* qT = (const float*)d_in[1];
  const float* kT = (const float*)d_in[2];
  const float* vT = (const float*)d_in[3];
  const int* rows = (const int*)d_in[4];
  const int* cols = (const int*)d_in[5];

  if (in_sizes[1] != LAT * LAT) return;   // kernel specialized for latdim=128
  const int N = in_sizes[0] / LAT;
  const int E = in_sizes[4];

  float* outRes = (float*)d_out;                    // [N,128]; temporarily holds Q
  float* outAtt = outRes + (size_t)N * LAT;         // [E,4]

  // workspace carve-up
  char* w = (char*)d_ws;
  size_t need = (size_t)N * 256 * 4 + (size_t)N * 4 * 3 + 1024 * 4 + (size_t)E * 8;
  if (ws_size < need) return;
  float* KV = (float*)w;      w += (size_t)N * 256 * 4;   // K|V interleaved rows
  int* counts = (int*)w;      w += (size_t)N * 4;
  int* starts = (int*)w;      w += (size_t)N * 4;
  int* cursor = (int*)w;      w += (size_t)N * 4;
  int* bsums  = (int*)w;      w += 1024 * 4;
  int2* epack = (int2*)w;     w += (size_t)E * 8;         // (orig edge id, col)

  hipMemsetAsync(counts, 0, (size_t)N * 4, stream);

  // per-node projections: Q -> outRes (stash), K|V -> interleaved workspace
  dim3 pg((N + 63) / 64, 3);
  proj_kernel<<<pg, 256, 0, stream>>>(embeds, qT, kT, vT, outRes, KV, N);

  // CSR of edges bucketed by destination (rows)
  deg_kernel<<<(E + 255) / 256, 256, 0, stream>>>(rows, counts, E);
  int nb = (N + 1023) / 1024;
  scan1_kernel<<<nb, 1024, 0, stream>>>(counts, starts, bsums, N);
  scan2_kernel<<<1, 1024, 0, stream>>>(bsums, nb);
  scan3_kernel<<<(N + 255) / 256, 256, 0, stream>>>(starts, bsums, cursor, N);
  fill_kernel<<<(E + 255) / 256, 256, 0, stream>>>(rows, cols, cursor, epack, E);

  // fused single-pass attention + aggregation + normalization (no atomics)
  attn_kernel<<<(N + 3) / 4, 256, 0, stream>>>(KV, starts, counts, epack,
                                               outRes, outAtt, N);
}

// Round 6
// 590.115 us; speedup vs baseline: 1.2185x; 1.2185x over previous
//
#include <hip/hip_runtime.h>

#define LAT 128
#define CAP 256   // per-node LDS cache of exp(att); deg>CAP falls back to recompute

typedef __attribute__((ext_vector_type(8))) short bfrag;
typedef __attribute__((ext_vector_type(4))) float f32x4;

__device__ inline unsigned short f2bf(float f) {
  unsigned u = __float_as_uint(f);
  unsigned r = u + 0x7FFFu + ((u >> 16) & 1u);   // round-to-nearest-even
  return (unsigned short)(r >> 16);
}

// ---- W fragment prep: W[128][128] fp32 -> hi/lo bf16 packed in MFMA B-frag order ----
// idx = ((s*8+t)*64 + l)*8 + i  <->  k = s*32 + (l>>4)*8 + i,  c = t*16 + (l&15)
__global__ __launch_bounds__(256) void wprep_kernel(
    const float* __restrict__ Wq, const float* __restrict__ Wk, const float* __restrict__ Wv,
    unsigned short* __restrict__ whi, unsigned short* __restrict__ wlo)
{
  int gid = blockIdx.x * 256 + threadIdx.x;          // 3 * 16384 total
  if (gid >= 3 * 16384) return;
  int mat = gid >> 14;
  int idx = gid & 16383;
  int i = idx & 7;
  int l = (idx >> 3) & 63;
  int st = idx >> 9;                                  // s*8 + t
  int k = (st >> 3) * 32 + ((l >> 4) << 3) + i;
  int c = (st & 7) * 16 + (l & 15);
  const float* W = (mat == 0) ? Wq : (mat == 1) ? Wk : Wv;
  float f = W[k * LAT + c];
  unsigned short h = f2bf(f);
  float fh = __uint_as_float((unsigned)h << 16);
  whi[gid] = h;
  wlo[gid] = f2bf(f - fh);
}

// ---------------- projection GEMM v5: bf16x3 MFMA ----------------
// Grid (ceil(N/64), 3 mats), 256 thr = 4 waves; wave w computes rows n0+16w..+15,
// all 128 cols. C = Ah*Wh + Al*Wh + Ah*Wl  (error ~1e-4 logit, fp32-equivalent).
__global__ __launch_bounds__(256) void proj_kernel(
    const float* __restrict__ A,
    const unsigned short* __restrict__ whi, const unsigned short* __restrict__ wlo,
    float* __restrict__ Cq, float* __restrict__ Ckv, int N)
{
  __shared__ unsigned short whiL[16384];   // 32 KB
  __shared__ unsigned short wloL[16384];   // 32 KB
  const int t = threadIdx.x;
  const int n0 = blockIdx.x * 64;
  const int mat = blockIdx.y;
  const unsigned short* wh = whi + mat * 16384;
  const unsigned short* wl = wlo + mat * 16384;
  // stage W frags: 64 KB = 4096 float4, 16 per thread, coalesced
  #pragma unroll
  for (int it = 0; it < 8; ++it) {
    int o = (it * 256 + t) * 8;           // ushort index (8 ushort = 16 B)
    *(float4*)&whiL[o] = *(const float4*)&wh[o];
    *(float4*)&wloL[o] = *(const float4*)&wl[o];
  }

  const int w = t >> 6, lane = t & 63;
  const int rowbase = n0 + w * 16;
  int arow = rowbase + (lane & 15);
  if (arow >= N) arow = N - 1;            // clamp loads; stores are guarded
  const int khalf = lane >> 4;            // 0..3

  // A fragments: row = lane&15, k = khalf*8 + i (same k formula as B frags)
  bfrag Ah[4], Al[4];
  #pragma unroll
  for (int s = 0; s < 4; ++s) {
    const float* ap = A + (size_t)arow * LAT + s * 32 + khalf * 8;
    float4 x0 = *(const float4*)ap;
    float4 x1 = *(const float4*)(ap + 4);
    float xs[8] = {x0.x, x0.y, x0.z, x0.w, x1.x, x1.y, x1.z, x1.w};
    #pragma unroll
    for (int i = 0; i < 8; ++i) {
      unsigned short h = f2bf(xs[i]);
      float fh = __uint_as_float((unsigned)h << 16);
      Ah[s][i] = (short)h;
      Al[s][i] = (short)f2bf(xs[i] - fh);
    }
  }
  __syncthreads();

  float* Cbase; int stride, cofs;
  if (mat == 0) { Cbase = Cq;  stride = LAT; cofs = 0; }
  else          { Cbase = Ckv; stride = 256; cofs = (mat == 2) ? 128 : 0; }

  #pragma unroll
  for (int tt = 0; tt < 8; ++tt) {
    f32x4 acc = {0.f, 0.f, 0.f, 0.f};
    #pragma unroll
    for (int s = 0; s < 4; ++s) {
      int o = ((s * 8 + tt) * 64 + lane) * 8;
      bfrag bh = *(bfrag*)&whiL[o];
      bfrag bl = *(bfrag*)&wloL[o];
      acc = __builtin_amdgcn_mfma_f32_16x16x32_bf16(Ah[s], bh, acc, 0, 0, 0);
      acc = __builtin_amdgcn_mfma_f32_16x16x32_bf16(Al[s], bh, acc, 0, 0, 0);
      acc = __builtin_amdgcn_mfma_f32_16x16x32_bf16(Ah[s], bl, acc, 0, 0, 0);
    }
    // C/D layout (verified): col = lane&15, row = (lane>>4)*4 + reg
    int col = cofs + tt * 16 + (lane & 15);
    int r0 = rowbase + (lane >> 4) * 4;
    #pragma unroll
    for (int r = 0; r < 4; ++r) {
      int row = r0 + r;
      if (row < N) Cbase[(size_t)row * stride + col] = acc[r];
    }
  }
}

// ---------------- CSR build ----------------
__global__ __launch_bounds__(256) void deg_kernel(const int* __restrict__ rows,
                                                  int* __restrict__ counts, int E) {
  int i = blockIdx.x * 256 + threadIdx.x;
  if (i < E) atomicAdd(&counts[rows[i]], 1);
}

__global__ __launch_bounds__(1024) void scan1_kernel(const int* __restrict__ counts,
                                                     int* __restrict__ starts,
                                                     int* __restrict__ bsums, int N) {
  __shared__ int sh[1024];
  int t = threadIdx.x;
  int i = blockIdx.x * 1024 + t;
  int v = (i < N) ? counts[i] : 0;
  sh[t] = v; __syncthreads();
  for (int off = 1; off < 1024; off <<= 1) {
    int x = (t >= off) ? sh[t - off] : 0;
    __syncthreads();
    sh[t] += x;
    __syncthreads();
  }
  if (i < N) starts[i] = sh[t] - v;
  if (t == 1023) bsums[blockIdx.x] = sh[t];
}

__global__ __launch_bounds__(1024) void scan2_kernel(int* __restrict__ bsums, int nb) {
  __shared__ int sh[1024];
  int t = threadIdx.x;
  int v = (t < nb) ? bsums[t] : 0;
  sh[t] = v; __syncthreads();
  for (int off = 1; off < 1024; off <<= 1) {
    int x = (t >= off) ? sh[t - off] : 0;
    __syncthreads();
    sh[t] += x;
    __syncthreads();
  }
  if (t < nb) bsums[t] = sh[t] - v;
}

__global__ __launch_bounds__(256) void scan3_kernel(int* __restrict__ starts,
                                                    const int* __restrict__ bsums,
                                                    int* __restrict__ cursor, int N) {
  int i = blockIdx.x * 256 + threadIdx.x;
  if (i < N) {
    int s = starts[i] + bsums[i >> 10];
    starts[i] = s;
    cursor[i] = s;
  }
}

__global__ __launch_bounds__(256) void fill_kernel(const int* __restrict__ rows,
                                                   const int* __restrict__ cols,
                                                   int* __restrict__ cursor,
                                                   int* __restrict__ eidx,
                                                   int* __restrict__ ecol, int E) {
  int i = blockIdx.x * 256 + threadIdx.x;
  if (i < E) {
    int p = atomicAdd(&cursor[rows[i]], 1);
    eidx[p] = i;
    ecol[p] = cols[i];
  }
}

// ---------------- fused attention (R4-measured best: 253 us, VGPR 32, occ 73%) ----
__global__ __launch_bounds__(256) void attn_kernel(
    const float* __restrict__ KV,
    const int* __restrict__ starts, const int* __restrict__ counts,
    const int* __restrict__ eidx, const int* __restrict__ ecol,
    float* __restrict__ outRes,    // in: Q rows (stashed); out: result
    float* __restrict__ outAtt,    // normalized attention [E][4]
    int N)
{
  __shared__ float eaL[4][CAP][4];   // [wave][edge idx][head]
  const int w = threadIdx.x >> 6;
  const int lane = threadIdx.x & 63;
  const int n = blockIdx.x * 4 + w;
  if (n >= N) return;                 // whole-wave exit; no __syncthreads below
  const int g = lane & 15;
  const int s = lane >> 4;
  const int start = starts[n];
  const int deg = counts[n];

  const float4 q0 = *(const float4*)(outRes + (size_t)n * LAT + g * 8);
  const float4 q1 = *(const float4*)(outRes + (size_t)n * LAT + g * 8 + 4);

  float denom = 0.f;
  float acc[8] = {};
  for (int base = 0; base < deg; base += 64) {
    int j = base + lane;
    int c_l = 0;
    if (j < deg) c_l = ecol[start + j];
    int m = deg - base; if (m > 64) m = 64;
    int steps = (m + 3) >> 2;
    #pragma unroll 2
    for (int st = 0; st < steps; ++st) {
      int jj = st * 4 + s;
      int c = __shfl(c_l, jj);
      bool valid = (jj < m);
      const float* kv = KV + (size_t)c * 256;
      float4 k0 = *(const float4*)(kv + g * 8);
      float4 k1 = *(const float4*)(kv + g * 8 + 4);
      float4 v0 = *(const float4*)(kv + 128 + g * 8);
      float4 v1 = *(const float4*)(kv + 128 + g * 8 + 4);
      float p = q0.x * k0.x + q0.y * k0.y + q0.z * k0.z + q0.w * k0.w
              + q1.x * k1.x + q1.y * k1.y + q1.z * k1.z + q1.w * k1.w;
      p += __shfl_xor(p, 1);
      p += __shfl_xor(p, 2);               // head-group dot complete
      p = fminf(fmaxf(p, -10.f), 10.f);
      float ea = valid ? __expf(p) : 0.f;
      denom += ea;
      acc[0] += ea * v0.x; acc[1] += ea * v0.y; acc[2] += ea * v0.z; acc[3] += ea * v0.w;
      acc[4] += ea * v1.x; acc[5] += ea * v1.y; acc[6] += ea * v1.z; acc[7] += ea * v1.w;
      int idx = base + jj;
      if (valid && (g & 3) == 0 && idx < CAP) eaL[w][idx][g >> 2] = ea;
    }
  }
  // cross-slot reduction (bits 4,5)
  denom += __shfl_xor(denom, 16);
  denom += __shfl_xor(denom, 32);
  #pragma unroll
  for (int i = 0; i < 8; ++i) {
    acc[i] += __shfl_xor(acc[i], 16);
    acc[i] += __shfl_xor(acc[i], 32);
  }
  const float rden = 1.f / (denom + 1e-8f);

  if (lane < 16) {
    float4 r0 = make_float4(acc[0] * rden, acc[1] * rden, acc[2] * rden, acc[3] * rden);
    float4 r1 = make_float4(acc[4] * rden, acc[5] * rden, acc[6] * rden, acc[7] * rden);
    *(float4*)(outRes + (size_t)n * LAT + g * 8) = r0;
    *(float4*)(outRes + (size_t)n * LAT + g * 8 + 4) = r1;
  }

  // per-head reciprocal denominators for the float4 att writes
  const float r0 = __shfl(rden, 0);
  const float r1 = __shfl(rden, 4);
  const float r2 = __shfl(rden, 8);
  const float r3 = __shfl(rden, 12);

  // epilogue: normalized att for cached edges (one float4 scatter per edge)
  int capped = deg < CAP ? deg : CAP;
  for (int j = lane; j < capped; j += 64) {
    int e = eidx[start + j];
    float4 a = *(float4*)&eaL[w][j][0];
    a.x *= r0; a.y *= r1; a.z *= r2; a.w *= r3;
    *(float4*)(outAtt + (size_t)e * 4) = a;
  }

  // fallback for deg > CAP (practically never for Poisson(16) degrees)
  const float myr = (g >> 2) == 0 ? r0 : (g >> 2) == 1 ? r1 : (g >> 2) == 2 ? r2 : r3;
  for (int base = CAP; base < deg; base += 64) {
    int j = base + lane;
    int c_l = 0, e_l = 0;
    if (j < deg) { c_l = ecol[start + j]; e_l = eidx[start + j]; }
    int m = deg - base; if (m > 64) m = 64;
    int steps = (m + 3) >> 2;
    for (int st = 0; st < steps; ++st) {
      int jj = st * 4 + s;
      int c = __shfl(c_l, jj);
      int e = __shfl(e_l, jj);
      bool valid = (jj < m);
      const float* kv = KV + (size_t)c * 256;
      float4 k0 = *(const float4*)(kv + g * 8);
      float4 k1 = *(const float4*)(kv + g * 8 + 4);
      float p = q0.x * k0.x + q0.y * k0.y + q0.z * k0.z + q0.w * k0.w
              + q1.x * k1.x + q1.y * k1.y + q1.z * k1.z + q1.w * k1.w;
      p += __shfl_xor(p, 1);
      p += __shfl_xor(p, 2);
      p = fminf(fmaxf(p, -10.f), 10.f);
      float av = __expf(p) * myr;
      int lb = lane & 48;
      float4 o;
      o.x = __shfl(av, lb + 0);
      o.y = __shfl(av, lb + 4);
      o.z = __shfl(av, lb + 8);
      o.w = __shfl(av, lb + 12);
      if (valid && g == 0) *(float4*)(outAtt + (size_t)e * 4) = o;
    }
  }
}

// ---------------- launch ----------------
extern "C" void kernel_launch(void* const* d_in, const int* in_sizes, int n_in,
                              void* d_out, int out_size, void* d_ws, size_t ws_size,
                              hipStream_t stream) {
  const float* embeds = (const float*)d_in[0];
  const float* qT = (const float*)d_in[1];
  const float* kT = (const float*)d_in[2];
  const float* vT = (const float*)d_in[3];
  const int* rows = (const int*)d_in[4];
  const int* cols = (const int*)d_in[5];

  if (in_sizes[1] != LAT * LAT) return;   // kernel specialized for latdim=128
  const int N = in_sizes[0] / LAT;
  const int E = in_sizes[4];

  float* outRes = (float*)d_out;                    // [N,128]; temporarily holds Q
  float* outAtt = outRes + (size_t)N * LAT;         // [E,4]

  // workspace carve-up (all sub-offsets stay 16B-aligned)
  char* w = (char*)d_ws;
  size_t need = (size_t)N * 1024 + (size_t)N * 12 + 4096 + (size_t)E * 8 + 2 * 98304;
  if (ws_size < need) return;
  float* KV = (float*)w;            w += (size_t)N * 256 * 4;   // K|V interleaved rows
  int* counts = (int*)w;            w += (size_t)N * 4;
  int* starts = (int*)w;            w += (size_t)N * 4;
  int* cursor = (int*)w;            w += (size_t)N * 4;
  int* bsums  = (int*)w;            w += 1024 * 4;
  int* eidx   = (int*)w;            w += (size_t)E * 4;
  int* ecol   = (int*)w;            w += (size_t)E * 4;
  unsigned short* whi = (unsigned short*)w;  w += 3 * 16384 * 2;
  unsigned short* wlo = (unsigned short*)w;  w += 3 * 16384 * 2;

  hipMemsetAsync(counts, 0, (size_t)N * 4, stream);

  // W -> bf16 hi/lo fragments (frag-ordered), then MFMA projections
  wprep_kernel<<<192, 256, 0, stream>>>(qT, kT, vT, whi, wlo);
  dim3 pg((N + 63) / 64, 3);
  proj_kernel<<<pg, 256, 0, stream>>>(embeds, whi, wlo, outRes, KV, N);

  // CSR of edges bucketed by destination (rows)
  deg_kernel<<<(E + 255) / 256, 256, 0, stream>>>(rows, counts, E);
  int nb = (N + 1023) / 1024;
  scan1_kernel<<<nb, 1024, 0, stream>>>(counts, starts, bsums, N);
  scan2_kernel<<<1, 1024, 0, stream>>>(bsums, nb);
  scan3_kernel<<<(N + 255) / 256, 256, 0, stream>>>(starts, bsums, cursor, N);
  fill_kernel<<<(E + 255) / 256, 256, 0, stream>>>(rows, cols, cursor, eidx, ecol, E);

  // fused single-pass attention + aggregation + normalization (no atomics)
  attn_kernel<<<(N + 3) / 4, 256, 0, stream>>>(KV, starts, counts, eidx, ecol,
                                               outRes, outAtt, N);
}